// Round 1
// baseline (1465.591 us; speedup 1.0000x reference)
//
#include <hip/hip_runtime.h>

#define N_NODES 100000
#define N_EDGES 1600000
#define IN_F 256
#define OUT_F 128

// ---------------------------------------------------------------------------
// GEMM: support[N_NODES, 128] = X[N_NODES, 256] @ W[256, 128]   (fp32)
// Tile: BM=64, BN=128, BK=32, 256 threads, each thread 8x4 micro-tile.
// ---------------------------------------------------------------------------
__global__ __launch_bounds__(256) void gemm_xw_kernel(const float* __restrict__ X,
                                                      const float* __restrict__ W,
                                                      float* __restrict__ support) {
    __shared__ float Xs[64][33];     // +1 pad
    __shared__ float Ws[32][128];

    const int block_row = blockIdx.x * 64;
    const int tid = threadIdx.x;
    const int tr = tid >> 5;         // 0..7  (row group)
    const int tc = tid & 31;         // 0..31 (col group)

    float acc[8][4];
#pragma unroll
    for (int i = 0; i < 8; ++i)
#pragma unroll
        for (int j = 0; j < 4; ++j) acc[i][j] = 0.f;

    for (int k0 = 0; k0 < IN_F; k0 += 32) {
        // stage X tile: 64x32 floats, 8 per thread, coalesced in k
#pragma unroll
        for (int i = 0; i < 8; ++i) {
            int idx = tid + i * 256;
            int r = idx >> 5, c = idx & 31;
            int grow = block_row + r;
            Xs[r][c] = (grow < N_NODES) ? X[grow * IN_F + k0 + c] : 0.f;
        }
        // stage W tile: 32x128 floats, 16 per thread, coalesced
#pragma unroll
        for (int i = 0; i < 16; ++i) {
            int idx = tid + i * 256;
            int r = idx >> 7, c = idx & 127;
            Ws[r][c] = W[(k0 + r) * OUT_F + c];
        }
        __syncthreads();

#pragma unroll
        for (int k = 0; k < 32; ++k) {
            float a[8];
#pragma unroll
            for (int i = 0; i < 8; ++i) a[i] = Xs[tr * 8 + i][k];
            float4 bv = *(const float4*)&Ws[k][tc * 4];
#pragma unroll
            for (int i = 0; i < 8; ++i) {
                acc[i][0] += a[i] * bv.x;
                acc[i][1] += a[i] * bv.y;
                acc[i][2] += a[i] * bv.z;
                acc[i][3] += a[i] * bv.w;
            }
        }
        __syncthreads();
    }

#pragma unroll
    for (int i = 0; i < 8; ++i) {
        int grow = block_row + tr * 8 + i;
        if (grow < N_NODES) {
            float4 v = {acc[i][0], acc[i][1], acc[i][2], acc[i][3]};
            *(float4*)&support[grow * OUT_F + tc * 4] = v;
        }
    }
}

// ---------------------------------------------------------------------------
// Init: out[n][f] = b[f]
// ---------------------------------------------------------------------------
__global__ __launch_bounds__(256) void bias_init_kernel(const float* __restrict__ b,
                                                        float* __restrict__ out) {
    int idx = blockIdx.x * blockDim.x + threadIdx.x;   // one float4 per thread
    // total float4s = N_NODES*128/4 = 3,200,000
    int col4 = (idx & 31);                              // 32 float4 per row
    const float4* b4 = (const float4*)b;
    float4 v = b4[col4];
    ((float4*)out)[idx] = v;
}

// ---------------------------------------------------------------------------
// Scatter: for each edge e: out[row] += val * support[col]   (atomic)
// One wave (64 lanes) per edge; lane handles 2 columns (float2).
// ---------------------------------------------------------------------------
__global__ __launch_bounds__(256) void scatter_kernel(const int* __restrict__ erow,
                                                      const int* __restrict__ ecol,
                                                      const float* __restrict__ eval,
                                                      const float* __restrict__ support,
                                                      float* __restrict__ out) {
    const int wave = (blockIdx.x * blockDim.x + threadIdx.x) >> 6;
    const int lane = threadIdx.x & 63;
    const int nwaves = (gridDim.x * blockDim.x) >> 6;

    for (int e = wave; e < N_EDGES; e += nwaves) {
        const int row = erow[e];
        const int col = ecol[e];
        const float val = eval[e];
        float2 s = *(const float2*)&support[col * OUT_F + lane * 2];
        float* dst = &out[row * OUT_F + lane * 2];
        atomicAdd(dst, val * s.x);
        atomicAdd(dst + 1, val * s.y);
    }
}

extern "C" void kernel_launch(void* const* d_in, const int* in_sizes, int n_in,
                              void* d_out, int out_size, void* d_ws, size_t ws_size,
                              hipStream_t stream) {
    const float* x        = (const float*)d_in[0];
    const int*   edge_row = (const int*)d_in[1];
    const int*   edge_col = (const int*)d_in[2];
    const float* edge_val = (const float*)d_in[3];
    const float* weight   = (const float*)d_in[4];
    const float* bias     = (const float*)d_in[5];
    float* out = (float*)d_out;

    float* support = (float*)d_ws;   // N_NODES * OUT_F floats = 51.2 MB

    // 1) support = X @ W
    dim3 gemm_grid((N_NODES + 63) / 64);
    gemm_xw_kernel<<<gemm_grid, 256, 0, stream>>>(x, weight, support);

    // 2) out = b (broadcast)
    int total4 = N_NODES * OUT_F / 4;                 // 3,200,000 float4
    bias_init_kernel<<<total4 / 256, 256, 0, stream>>>(bias, out);

    // 3) out += A @ support (atomic scatter, one wave per edge)
    scatter_kernel<<<2048, 256, 0, stream>>>(edge_row, edge_col, edge_val,
                                             support, out);
}

// Round 2
// 709.386 us; speedup vs baseline: 2.0660x; 2.0660x over previous
//
#include <hip/hip_runtime.h>

#define N_NODES 100000
#define N_EDGES 1600000
#define IN_F 256
#define OUT_F 128

// ---------------------------------------------------------------------------
// GEMM: support[N_NODES, 128] = X[N_NODES, 256] @ W[256, 128]   (fp32)
// ---------------------------------------------------------------------------
__global__ __launch_bounds__(256) void gemm_xw_kernel(const float* __restrict__ X,
                                                      const float* __restrict__ W,
                                                      float* __restrict__ support) {
    __shared__ float Xs[64][33];
    __shared__ float Ws[32][128];

    const int block_row = blockIdx.x * 64;
    const int tid = threadIdx.x;
    const int tr = tid >> 5;
    const int tc = tid & 31;

    float acc[8][4];
#pragma unroll
    for (int i = 0; i < 8; ++i)
#pragma unroll
        for (int j = 0; j < 4; ++j) acc[i][j] = 0.f;

    for (int k0 = 0; k0 < IN_F; k0 += 32) {
#pragma unroll
        for (int i = 0; i < 8; ++i) {
            int idx = tid + i * 256;
            int r = idx >> 5, c = idx & 31;
            int grow = block_row + r;
            Xs[r][c] = (grow < N_NODES) ? X[grow * IN_F + k0 + c] : 0.f;
        }
#pragma unroll
        for (int i = 0; i < 16; ++i) {
            int idx = tid + i * 256;
            int r = idx >> 7, c = idx & 127;
            Ws[r][c] = W[(k0 + r) * OUT_F + c];
        }
        __syncthreads();

#pragma unroll
        for (int k = 0; k < 32; ++k) {
            float a[8];
#pragma unroll
            for (int i = 0; i < 8; ++i) a[i] = Xs[tr * 8 + i][k];
            float4 bv = *(const float4*)&Ws[k][tc * 4];
#pragma unroll
            for (int i = 0; i < 8; ++i) {
                acc[i][0] += a[i] * bv.x;
                acc[i][1] += a[i] * bv.y;
                acc[i][2] += a[i] * bv.z;
                acc[i][3] += a[i] * bv.w;
            }
        }
        __syncthreads();
    }

#pragma unroll
    for (int i = 0; i < 8; ++i) {
        int grow = block_row + tr * 8 + i;
        if (grow < N_NODES) {
            float4 v = {acc[i][0], acc[i][1], acc[i][2], acc[i][3]};
            *(float4*)&support[grow * OUT_F + tc * 4] = v;
        }
    }
}

// ---------------------------------------------------------------------------
// Phase A: histogram of destination rows
// ---------------------------------------------------------------------------
__global__ __launch_bounds__(256) void hist_kernel(const int* __restrict__ erow,
                                                   int* __restrict__ hist) {
    int e = blockIdx.x * blockDim.x + threadIdx.x;
    if (e < N_EDGES) atomicAdd(&hist[erow[e]], 1);
}

// ---------------------------------------------------------------------------
// Phase B: exclusive scan of hist (single 1024-thread workgroup)
// Each thread serially owns a chunk of 98 rows; LDS Hillis-Steele over the
// 1024 per-thread partials.
// ---------------------------------------------------------------------------
__global__ __launch_bounds__(1024) void scan_kernel(const int* __restrict__ hist,
                                                    int* __restrict__ offsets,
                                                    int* __restrict__ cursor) {
    __shared__ int partial[1024];
    const int tid = threadIdx.x;
    const int CH = 98;                       // 1024*98 = 100352 >= N_NODES
    const int base = tid * CH;

    int s = 0;
    for (int i = 0; i < CH; ++i) {
        int idx = base + i;
        if (idx < N_NODES) s += hist[idx];
    }
    partial[tid] = s;
    __syncthreads();

    for (int off = 1; off < 1024; off <<= 1) {
        int v = (tid >= off) ? partial[tid - off] : 0;
        __syncthreads();
        partial[tid] += v;
        __syncthreads();
    }
    int run = (tid == 0) ? 0 : partial[tid - 1];

    for (int i = 0; i < CH; ++i) {
        int idx = base + i;
        if (idx < N_NODES) {
            offsets[idx] = run;
            cursor[idx] = run;
            run += hist[idx];
        }
    }
    if (tid == 1023) offsets[N_NODES] = run;   // == N_EDGES
}

// ---------------------------------------------------------------------------
// Phase C: scatter edges into row-sorted order as packed (val<<32 | col)
// ---------------------------------------------------------------------------
__global__ __launch_bounds__(256) void sort_kernel(const int* __restrict__ erow,
                                                   const int* __restrict__ ecol,
                                                   const float* __restrict__ eval,
                                                   int* __restrict__ cursor,
                                                   unsigned long long* __restrict__ sorted) {
    int e = blockIdx.x * blockDim.x + threadIdx.x;
    if (e >= N_EDGES) return;
    int row = erow[e];
    int pos = atomicAdd(&cursor[row], 1);
    unsigned long long rec =
        ((unsigned long long)__float_as_uint(eval[e]) << 32) | (unsigned int)ecol[e];
    sorted[pos] = rec;
}

// ---------------------------------------------------------------------------
// Phase D: SpMM — one wave per row; register accumulation; bias folded in.
// Lane handles 2 columns (float2).
// ---------------------------------------------------------------------------
__global__ __launch_bounds__(256) void spmm_kernel(const int* __restrict__ offsets,
                                                   const unsigned long long* __restrict__ sorted,
                                                   const float* __restrict__ support,
                                                   const float* __restrict__ b,
                                                   float* __restrict__ out) {
    const int wave = blockIdx.x * 4 + (threadIdx.x >> 6);
    const int lane = threadIdx.x & 63;
    if (wave >= N_NODES) return;

    const int row = wave;
    const int start = offsets[row];
    const int end = offsets[row + 1];

    float2 acc = *(const float2*)&b[lane * 2];

    int e = start;
    // unroll-by-2 for a little ILP on the gather chain
    for (; e + 1 < end; e += 2) {
        unsigned long long r0 = sorted[e];
        unsigned long long r1 = sorted[e + 1];
        int c0 = (int)(r0 & 0xffffffffu);
        int c1 = (int)(r1 & 0xffffffffu);
        float v0 = __uint_as_float((unsigned int)(r0 >> 32));
        float v1 = __uint_as_float((unsigned int)(r1 >> 32));
        float2 s0 = *(const float2*)&support[c0 * OUT_F + lane * 2];
        float2 s1 = *(const float2*)&support[c1 * OUT_F + lane * 2];
        acc.x += v0 * s0.x + v1 * s1.x;
        acc.y += v0 * s0.y + v1 * s1.y;
    }
    if (e < end) {
        unsigned long long r0 = sorted[e];
        int c0 = (int)(r0 & 0xffffffffu);
        float v0 = __uint_as_float((unsigned int)(r0 >> 32));
        float2 s0 = *(const float2*)&support[c0 * OUT_F + lane * 2];
        acc.x += v0 * s0.x;
        acc.y += v0 * s0.y;
    }

    *(float2*)&out[row * OUT_F + lane * 2] = acc;
}

extern "C" void kernel_launch(void* const* d_in, const int* in_sizes, int n_in,
                              void* d_out, int out_size, void* d_ws, size_t ws_size,
                              hipStream_t stream) {
    const float* x        = (const float*)d_in[0];
    const int*   edge_row = (const int*)d_in[1];
    const int*   edge_col = (const int*)d_in[2];
    const float* edge_val = (const float*)d_in[3];
    const float* weight   = (const float*)d_in[4];
    const float* bias     = (const float*)d_in[5];
    float* out = (float*)d_out;

    // workspace layout (4-byte units; sorted kept 8B-aligned)
    float* support = (float*)d_ws;                            // 12,800,000 f
    int* hist    = (int*)d_ws + 12800000;                     // 100,000
    int* offsets = hist + N_NODES;                            // 100,001 (+1 pad)
    int* cursor  = offsets + N_NODES + 2;                     // 100,000
    unsigned long long* sorted =
        (unsigned long long*)(cursor + N_NODES);              // 1,600,000 u64
    // total ≈ 65.2 MB

    // 1) support = X @ W
    gemm_xw_kernel<<<dim3((N_NODES + 63) / 64), 256, 0, stream>>>(x, weight, support);

    // 2) zero histogram
    hipMemsetAsync(hist, 0, N_NODES * sizeof(int), stream);

    // 3) histogram of rows
    hist_kernel<<<dim3((N_EDGES + 255) / 256), 256, 0, stream>>>(edge_row, hist);

    // 4) exclusive scan -> offsets, cursor
    scan_kernel<<<dim3(1), 1024, 0, stream>>>(hist, offsets, cursor);

    // 5) bin edges by row
    sort_kernel<<<dim3((N_EDGES + 255) / 256), 256, 0, stream>>>(edge_row, edge_col,
                                                                 edge_val, cursor, sorted);

    // 6) SpMM: one wave per row, bias folded in
    spmm_kernel<<<dim3(N_NODES / 4), 256, 0, stream>>>(offsets, sorted, support, bias, out);
}

// Round 3
// 462.799 us; speedup vs baseline: 3.1668x; 1.5328x over previous
//
#include <hip/hip_runtime.h>

#define N_NODES 100000
#define N_EDGES 1600000
#define IN_F 256
#define OUT_F 128
#define SCAN_NB 98            // ceil(100000 / 1024)

// ---------------------------------------------------------------------------
// GEMM: support[N_NODES, 128] = X[N_NODES, 256] @ W[256, 128]   (fp32)
// ---------------------------------------------------------------------------
__global__ __launch_bounds__(256) void gemm_xw_kernel(const float* __restrict__ X,
                                                      const float* __restrict__ W,
                                                      float* __restrict__ support) {
    __shared__ float Xs[64][33];
    __shared__ float Ws[32][128];

    const int block_row = blockIdx.x * 64;
    const int tid = threadIdx.x;
    const int tr = tid >> 5;
    const int tc = tid & 31;

    float acc[8][4];
#pragma unroll
    for (int i = 0; i < 8; ++i)
#pragma unroll
        for (int j = 0; j < 4; ++j) acc[i][j] = 0.f;

    for (int k0 = 0; k0 < IN_F; k0 += 32) {
#pragma unroll
        for (int i = 0; i < 8; ++i) {
            int idx = tid + i * 256;
            int r = idx >> 5, c = idx & 31;
            int grow = block_row + r;
            Xs[r][c] = (grow < N_NODES) ? X[grow * IN_F + k0 + c] : 0.f;
        }
#pragma unroll
        for (int i = 0; i < 16; ++i) {
            int idx = tid + i * 256;
            int r = idx >> 7, c = idx & 127;
            Ws[r][c] = W[(k0 + r) * OUT_F + c];
        }
        __syncthreads();

#pragma unroll
        for (int k = 0; k < 32; ++k) {
            float a[8];
#pragma unroll
            for (int i = 0; i < 8; ++i) a[i] = Xs[tr * 8 + i][k];
            float4 bv = *(const float4*)&Ws[k][tc * 4];
#pragma unroll
            for (int i = 0; i < 8; ++i) {
                acc[i][0] += a[i] * bv.x;
                acc[i][1] += a[i] * bv.y;
                acc[i][2] += a[i] * bv.z;
                acc[i][3] += a[i] * bv.w;
            }
        }
        __syncthreads();
    }

#pragma unroll
    for (int i = 0; i < 8; ++i) {
        int grow = block_row + tr * 8 + i;
        if (grow < N_NODES) {
            float4 v = {acc[i][0], acc[i][1], acc[i][2], acc[i][3]};
            *(float4*)&support[grow * OUT_F + tc * 4] = v;
        }
    }
}

// ---------------------------------------------------------------------------
// Phase A: histogram of destination rows
// ---------------------------------------------------------------------------
__global__ __launch_bounds__(256) void hist_kernel(const int* __restrict__ erow,
                                                   int* __restrict__ hist) {
    int e = blockIdx.x * blockDim.x + threadIdx.x;
    if (e < N_EDGES) atomicAdd(&hist[erow[e]], 1);
}

// ---------------------------------------------------------------------------
// Phase B1: per-block scan (1024 rows/block). Writes local-exclusive values
// into offsets[] and the block total into blocksums[].
// ---------------------------------------------------------------------------
__global__ __launch_bounds__(1024) void scan1_kernel(const int* __restrict__ hist,
                                                     int* __restrict__ offsets,
                                                     int* __restrict__ blocksums) {
    __shared__ int partial[1024];
    const int tid = threadIdx.x;
    const int idx = blockIdx.x * 1024 + tid;

    int v = (idx < N_NODES) ? hist[idx] : 0;
    partial[tid] = v;
    __syncthreads();

#pragma unroll
    for (int off = 1; off < 1024; off <<= 1) {
        int t = (tid >= off) ? partial[tid - off] : 0;
        __syncthreads();
        partial[tid] += t;
        __syncthreads();
    }
    if (idx < N_NODES) offsets[idx] = partial[tid] - v;   // exclusive
    if (tid == 1023) blocksums[blockIdx.x] = partial[1023];
}

// ---------------------------------------------------------------------------
// Phase B2: scan the SCAN_NB block sums (single tiny block)
// ---------------------------------------------------------------------------
__global__ __launch_bounds__(128) void scan2_kernel(int* __restrict__ blocksums) {
    __shared__ int partial[128];
    const int tid = threadIdx.x;
    int v = (tid < SCAN_NB) ? blocksums[tid] : 0;
    partial[tid] = v;
    __syncthreads();
#pragma unroll
    for (int off = 1; off < 128; off <<= 1) {
        int t = (tid >= off) ? partial[tid - off] : 0;
        __syncthreads();
        partial[tid] += t;
        __syncthreads();
    }
    if (tid < SCAN_NB) blocksums[tid] = partial[tid] - v;  // exclusive
}

// ---------------------------------------------------------------------------
// Phase B3: add block offsets; produce final offsets + cursor
// ---------------------------------------------------------------------------
__global__ __launch_bounds__(1024) void scan3_kernel(int* __restrict__ offsets,
                                                     const int* __restrict__ blocksums,
                                                     int* __restrict__ cursor) {
    const int idx = blockIdx.x * 1024 + threadIdx.x;
    if (idx < N_NODES) {
        int off = offsets[idx] + blocksums[blockIdx.x];
        offsets[idx] = off;
        cursor[idx] = off;
    }
    if (idx == 0) offsets[N_NODES] = N_EDGES;   // total is static
}

// ---------------------------------------------------------------------------
// Phase C: scatter edges into row-sorted order as packed (val<<32 | col)
// ---------------------------------------------------------------------------
__global__ __launch_bounds__(256) void sort_kernel(const int* __restrict__ erow,
                                                   const int* __restrict__ ecol,
                                                   const float* __restrict__ eval,
                                                   int* __restrict__ cursor,
                                                   unsigned long long* __restrict__ sorted) {
    int e = blockIdx.x * blockDim.x + threadIdx.x;
    if (e >= N_EDGES) return;
    int row = erow[e];
    int pos = atomicAdd(&cursor[row], 1);
    unsigned long long rec =
        ((unsigned long long)__float_as_uint(eval[e]) << 32) | (unsigned int)ecol[e];
    sorted[pos] = rec;
}

// ---------------------------------------------------------------------------
// Phase D: SpMM — one wave per row; register accumulation; bias folded in.
// ---------------------------------------------------------------------------
__global__ __launch_bounds__(256) void spmm_kernel(const int* __restrict__ offsets,
                                                   const unsigned long long* __restrict__ sorted,
                                                   const float* __restrict__ support,
                                                   const float* __restrict__ b,
                                                   float* __restrict__ out) {
    const int wave = blockIdx.x * 4 + (threadIdx.x >> 6);
    const int lane = threadIdx.x & 63;
    if (wave >= N_NODES) return;

    const int row = wave;
    const int start = offsets[row];
    const int end = offsets[row + 1];

    float2 acc = *(const float2*)&b[lane * 2];

    int e = start;
    for (; e + 1 < end; e += 2) {
        unsigned long long r0 = sorted[e];
        unsigned long long r1 = sorted[e + 1];
        int c0 = (int)(r0 & 0xffffffffu);
        int c1 = (int)(r1 & 0xffffffffu);
        float v0 = __uint_as_float((unsigned int)(r0 >> 32));
        float v1 = __uint_as_float((unsigned int)(r1 >> 32));
        float2 s0 = *(const float2*)&support[c0 * OUT_F + lane * 2];
        float2 s1 = *(const float2*)&support[c1 * OUT_F + lane * 2];
        acc.x += v0 * s0.x + v1 * s1.x;
        acc.y += v0 * s0.y + v1 * s1.y;
    }
    if (e < end) {
        unsigned long long r0 = sorted[e];
        int c0 = (int)(r0 & 0xffffffffu);
        float v0 = __uint_as_float((unsigned int)(r0 >> 32));
        float2 s0 = *(const float2*)&support[c0 * OUT_F + lane * 2];
        acc.x += v0 * s0.x;
        acc.y += v0 * s0.y;
    }

    *(float2*)&out[row * OUT_F + lane * 2] = acc;
}

extern "C" void kernel_launch(void* const* d_in, const int* in_sizes, int n_in,
                              void* d_out, int out_size, void* d_ws, size_t ws_size,
                              hipStream_t stream) {
    const float* x        = (const float*)d_in[0];
    const int*   edge_row = (const int*)d_in[1];
    const int*   edge_col = (const int*)d_in[2];
    const float* edge_val = (const float*)d_in[3];
    const float* weight   = (const float*)d_in[4];
    const float* bias     = (const float*)d_in[5];
    float* out = (float*)d_out;

    // workspace layout (4-byte units; sorted kept 8B-aligned)
    float* support = (float*)d_ws;                            // 12,800,000 f
    int* hist    = (int*)d_ws + 12800000;                     // 100,000
    int* offsets = hist + N_NODES;                            // 100,001 (+pad)
    int* cursor  = offsets + N_NODES + 2;                     // 100,000
    int* blocksums = cursor + N_NODES;                        // 98 (+pad to even)
    unsigned long long* sorted =
        (unsigned long long*)(blocksums + 128);               // 1,600,000 u64
    // total ≈ 65.2 MB

    // 1) support = X @ W
    gemm_xw_kernel<<<dim3((N_NODES + 63) / 64), 256, 0, stream>>>(x, weight, support);

    // 2) zero histogram
    hipMemsetAsync(hist, 0, N_NODES * sizeof(int), stream);

    // 3) histogram of rows
    hist_kernel<<<dim3((N_EDGES + 255) / 256), 256, 0, stream>>>(edge_row, hist);

    // 4) hierarchical exclusive scan -> offsets, cursor
    scan1_kernel<<<dim3(SCAN_NB), 1024, 0, stream>>>(hist, offsets, blocksums);
    scan2_kernel<<<dim3(1), 128, 0, stream>>>(blocksums);
    scan3_kernel<<<dim3(SCAN_NB), 1024, 0, stream>>>(offsets, blocksums, cursor);

    // 5) bin edges by row
    sort_kernel<<<dim3((N_EDGES + 255) / 256), 256, 0, stream>>>(edge_row, edge_col,
                                                                 edge_val, cursor, sorted);

    // 6) SpMM: one wave per row, bias folded in
    spmm_kernel<<<dim3(N_NODES / 4), 256, 0, stream>>>(offsets, sorted, support, bias, out);
}

// Round 4
// 349.168 us; speedup vs baseline: 4.1974x; 1.3254x over previous
//
#include <hip/hip_runtime.h>

#define N_NODES 100000
#define N_EDGES 1600000
#define IN_F 256
#define OUT_F 128
#define SCAN_NB 98            // ceil(100000 / 1024)

typedef __attribute__((ext_vector_type(4))) float f32x4;
typedef __attribute__((ext_vector_type(8))) short bf16x8;

__device__ __forceinline__ unsigned short f2bf(float f) {
    unsigned u = __float_as_uint(f);
    unsigned r = u + 0x7FFF + ((u >> 16) & 1);    // round-to-nearest-even
    return (unsigned short)(r >> 16);
}

// ---------------------------------------------------------------------------
// W convert: Wt[n][k] = bf16(W[k][n])   (transposed so B-frags are contiguous)
// ---------------------------------------------------------------------------
__global__ __launch_bounds__(256) void wconv_kernel(const float* __restrict__ W,
                                                    unsigned short* __restrict__ Wt) {
    int idx = blockIdx.x * 256 + threadIdx.x;      // 32768 total
    int n = idx >> 8;
    int k = idx & 255;
    Wt[n * IN_F + k] = f2bf(W[k * OUT_F + n]);
}

// ---------------------------------------------------------------------------
// MFMA GEMM: support[100000,128] = X[100000,256] @ W  (A fp32->bf16 fused)
// 128x128 tile, BK=32, 256 threads = 4 waves (2x2), 64x64 per wave.
// LDS layout [kb][row][8] so every fragment read is one ds_read_b128.
// ---------------------------------------------------------------------------
__global__ __launch_bounds__(256) void gemm_mfma_kernel(const float* __restrict__ X,
                                                        const unsigned short* __restrict__ Wt,
                                                        float* __restrict__ support) {
    __shared__ __align__(16) unsigned short Albs[4][128][8];   // 8 KB
    __shared__ __align__(16) unsigned short Blbs[4][128][8];   // 8 KB

    const int tid = threadIdx.x;
    const int block_row = blockIdx.x * 128;

    // staging coords: 2 threads per row, 16 elems each
    const int srow = tid >> 1;          // 0..127
    const int shalf = tid & 1;          // 0/1 -> cols shalf*16 .. +15

    // compute coords
    const int wid = tid >> 6;           // 0..3
    const int lane = tid & 63;
    const int wr = wid >> 1, wc = wid & 1;
    const int fr = lane & 15;           // row (A) / col (B) within fragment
    const int kb = lane >> 4;           // k-block 0..3

    const int agrow = block_row + srow;
    const float* xrow = X + (long)agrow * IN_F;
    const unsigned short* wrow = Wt + srow * IN_F;   // srow doubles as B col

    f32x4 acc[4][4];
#pragma unroll
    for (int m = 0; m < 4; ++m)
#pragma unroll
        for (int n = 0; n < 4; ++n) acc[m][n] = (f32x4)0.f;

    for (int k0 = 0; k0 < IN_F; k0 += 32) {
        // ---- stage A (convert fp32 -> bf16) ----
        float4 f0, f1, f2, f3;
        if (agrow < N_NODES) {
            f0 = *(const float4*)&xrow[k0 + shalf * 16 + 0];
            f1 = *(const float4*)&xrow[k0 + shalf * 16 + 4];
            f2 = *(const float4*)&xrow[k0 + shalf * 16 + 8];
            f3 = *(const float4*)&xrow[k0 + shalf * 16 + 12];
        } else {
            f0 = f1 = f2 = f3 = make_float4(0.f, 0.f, 0.f, 0.f);
        }
        {
            bf16x8 p0, p1;
            p0[0] = (short)f2bf(f0.x); p0[1] = (short)f2bf(f0.y);
            p0[2] = (short)f2bf(f0.z); p0[3] = (short)f2bf(f0.w);
            p0[4] = (short)f2bf(f1.x); p0[5] = (short)f2bf(f1.y);
            p0[6] = (short)f2bf(f1.z); p0[7] = (short)f2bf(f1.w);
            p1[0] = (short)f2bf(f2.x); p1[1] = (short)f2bf(f2.y);
            p1[2] = (short)f2bf(f2.z); p1[3] = (short)f2bf(f2.w);
            p1[4] = (short)f2bf(f3.x); p1[5] = (short)f2bf(f3.y);
            p1[6] = (short)f2bf(f3.z); p1[7] = (short)f2bf(f3.w);
            *(bf16x8*)&Albs[shalf * 2][srow][0]     = p0;
            *(bf16x8*)&Albs[shalf * 2 + 1][srow][0] = p1;
        }
        // ---- stage B (already bf16, transposed) ----
        {
            bf16x8 b0 = *(const bf16x8*)&wrow[k0 + shalf * 16];
            bf16x8 b1 = *(const bf16x8*)&wrow[k0 + shalf * 16 + 8];
            *(bf16x8*)&Blbs[shalf * 2][srow][0]     = b0;
            *(bf16x8*)&Blbs[shalf * 2 + 1][srow][0] = b1;
        }
        __syncthreads();

        // ---- compute ----
        bf16x8 af[4], bfr[4];
#pragma unroll
        for (int m = 0; m < 4; ++m)
            af[m] = *(const bf16x8*)&Albs[kb][wr * 64 + m * 16 + fr][0];
#pragma unroll
        for (int n = 0; n < 4; ++n)
            bfr[n] = *(const bf16x8*)&Blbs[kb][wc * 64 + n * 16 + fr][0];
#pragma unroll
        for (int m = 0; m < 4; ++m)
#pragma unroll
            for (int n = 0; n < 4; ++n)
                acc[m][n] = __builtin_amdgcn_mfma_f32_16x16x32_bf16(af[m], bfr[n],
                                                                    acc[m][n], 0, 0, 0);
        __syncthreads();
    }

    // ---- epilogue: C/D layout col=lane&15, row=(lane>>4)*4+reg ----
    const int crow0 = (lane >> 4) * 4;
    const int ccol = lane & 15;
#pragma unroll
    for (int m = 0; m < 4; ++m) {
#pragma unroll
        for (int reg = 0; reg < 4; ++reg) {
            int grow = block_row + wr * 64 + m * 16 + crow0 + reg;
            if (grow < N_NODES) {
#pragma unroll
                for (int n = 0; n < 4; ++n) {
                    int gcol = wc * 64 + n * 16 + ccol;
                    support[(long)grow * OUT_F + gcol] = acc[m][n][reg];
                }
            }
        }
    }
}

// ---------------------------------------------------------------------------
// Phase A: histogram of destination rows
// ---------------------------------------------------------------------------
__global__ __launch_bounds__(256) void hist_kernel(const int* __restrict__ erow,
                                                   int* __restrict__ hist) {
    int e = blockIdx.x * blockDim.x + threadIdx.x;
    if (e < N_EDGES) atomicAdd(&hist[erow[e]], 1);
}

// ---------------------------------------------------------------------------
// Phase B1/B2/B3: hierarchical exclusive scan
// ---------------------------------------------------------------------------
__global__ __launch_bounds__(1024) void scan1_kernel(const int* __restrict__ hist,
                                                     int* __restrict__ offsets,
                                                     int* __restrict__ blocksums) {
    __shared__ int partial[1024];
    const int tid = threadIdx.x;
    const int idx = blockIdx.x * 1024 + tid;

    int v = (idx < N_NODES) ? hist[idx] : 0;
    partial[tid] = v;
    __syncthreads();

#pragma unroll
    for (int off = 1; off < 1024; off <<= 1) {
        int t = (tid >= off) ? partial[tid - off] : 0;
        __syncthreads();
        partial[tid] += t;
        __syncthreads();
    }
    if (idx < N_NODES) offsets[idx] = partial[tid] - v;
    if (tid == 1023) blocksums[blockIdx.x] = partial[1023];
}

__global__ __launch_bounds__(128) void scan2_kernel(int* __restrict__ blocksums) {
    __shared__ int partial[128];
    const int tid = threadIdx.x;
    int v = (tid < SCAN_NB) ? blocksums[tid] : 0;
    partial[tid] = v;
    __syncthreads();
#pragma unroll
    for (int off = 1; off < 128; off <<= 1) {
        int t = (tid >= off) ? partial[tid - off] : 0;
        __syncthreads();
        partial[tid] += t;
        __syncthreads();
    }
    if (tid < SCAN_NB) blocksums[tid] = partial[tid] - v;
}

__global__ __launch_bounds__(1024) void scan3_kernel(int* __restrict__ offsets,
                                                     const int* __restrict__ blocksums,
                                                     int* __restrict__ cursor) {
    const int idx = blockIdx.x * 1024 + threadIdx.x;
    if (idx < N_NODES) {
        int off = offsets[idx] + blocksums[blockIdx.x];
        offsets[idx] = off;
        cursor[idx] = off;
    }
    if (idx == 0) offsets[N_NODES] = N_EDGES;
}

// ---------------------------------------------------------------------------
// Phase C: scatter edges into row-sorted order as packed (val<<32 | col)
// ---------------------------------------------------------------------------
__global__ __launch_bounds__(256) void sort_kernel(const int* __restrict__ erow,
                                                   const int* __restrict__ ecol,
                                                   const float* __restrict__ eval,
                                                   int* __restrict__ cursor,
                                                   unsigned long long* __restrict__ sorted) {
    int e = blockIdx.x * blockDim.x + threadIdx.x;
    if (e >= N_EDGES) return;
    int row = erow[e];
    int pos = atomicAdd(&cursor[row], 1);
    unsigned long long rec =
        ((unsigned long long)__float_as_uint(eval[e]) << 32) | (unsigned int)ecol[e];
    sorted[pos] = rec;
}

// ---------------------------------------------------------------------------
// Phase D: SpMM — one wave per row; register accumulation; bias folded in.
// ---------------------------------------------------------------------------
__global__ __launch_bounds__(256) void spmm_kernel(const int* __restrict__ offsets,
                                                   const unsigned long long* __restrict__ sorted,
                                                   const float* __restrict__ support,
                                                   const float* __restrict__ b,
                                                   float* __restrict__ out) {
    const int wave = blockIdx.x * 4 + (threadIdx.x >> 6);
    const int lane = threadIdx.x & 63;
    if (wave >= N_NODES) return;

    const int row = wave;
    const int start = offsets[row];
    const int end = offsets[row + 1];

    float2 acc = *(const float2*)&b[lane * 2];

    int e = start;
    for (; e + 1 < end; e += 2) {
        unsigned long long r0 = sorted[e];
        unsigned long long r1 = sorted[e + 1];
        int c0 = (int)(r0 & 0xffffffffu);
        int c1 = (int)(r1 & 0xffffffffu);
        float v0 = __uint_as_float((unsigned int)(r0 >> 32));
        float v1 = __uint_as_float((unsigned int)(r1 >> 32));
        float2 s0 = *(const float2*)&support[c0 * OUT_F + lane * 2];
        float2 s1 = *(const float2*)&support[c1 * OUT_F + lane * 2];
        acc.x += v0 * s0.x + v1 * s1.x;
        acc.y += v0 * s0.y + v1 * s1.y;
    }
    if (e < end) {
        unsigned long long r0 = sorted[e];
        int c0 = (int)(r0 & 0xffffffffu);
        float v0 = __uint_as_float((unsigned int)(r0 >> 32));
        float2 s0 = *(const float2*)&support[c0 * OUT_F + lane * 2];
        acc.x += v0 * s0.x;
        acc.y += v0 * s0.y;
    }

    *(float2*)&out[row * OUT_F + lane * 2] = acc;
}

extern "C" void kernel_launch(void* const* d_in, const int* in_sizes, int n_in,
                              void* d_out, int out_size, void* d_ws, size_t ws_size,
                              hipStream_t stream) {
    const float* x        = (const float*)d_in[0];
    const int*   edge_row = (const int*)d_in[1];
    const int*   edge_col = (const int*)d_in[2];
    const float* edge_val = (const float*)d_in[3];
    const float* weight   = (const float*)d_in[4];
    const float* bias     = (const float*)d_in[5];
    float* out = (float*)d_out;

    // workspace layout (4-byte units; sorted kept 8B-aligned)
    float* support = (float*)d_ws;                            // 12,800,000 f
    int* hist    = (int*)d_ws + 12800000;                     // 100,000
    int* offsets = hist + N_NODES;                            // 100,001 (+pad)
    int* cursor  = offsets + N_NODES + 2;                     // 100,000
    int* blocksums = cursor + N_NODES;                        // 98 (pad 128)
    unsigned long long* sorted =
        (unsigned long long*)(blocksums + 128);               // 1,600,000 u64
    unsigned short* wt = (unsigned short*)(sorted + N_EDGES); // 32,768 bf16
    // total ≈ 65.3 MB

    // 0) W -> transposed bf16
    wconv_kernel<<<dim3(128), 256, 0, stream>>>(weight, wt);

    // 1) support = X @ W  (bf16 MFMA, conversion fused)
    gemm_mfma_kernel<<<dim3((N_NODES + 127) / 128), 256, 0, stream>>>(x, wt, support);

    // 2) zero histogram
    hipMemsetAsync(hist, 0, N_NODES * sizeof(int), stream);

    // 3) histogram of rows
    hist_kernel<<<dim3((N_EDGES + 255) / 256), 256, 0, stream>>>(edge_row, hist);

    // 4) hierarchical exclusive scan -> offsets, cursor
    scan1_kernel<<<dim3(SCAN_NB), 1024, 0, stream>>>(hist, offsets, blocksums);
    scan2_kernel<<<dim3(1), 128, 0, stream>>>(blocksums);
    scan3_kernel<<<dim3(SCAN_NB), 1024, 0, stream>>>(offsets, blocksums, cursor);

    // 5) bin edges by row
    sort_kernel<<<dim3((N_EDGES + 255) / 256), 256, 0, stream>>>(edge_row, edge_col,
                                                                 edge_val, cursor, sorted);

    // 6) SpMM: one wave per row, bias folded in
    spmm_kernel<<<dim3((N_NODES + 3) / 4), 256, 0, stream>>>(offsets, sorted, support, bias, out);
}

// Round 5
// 177.526 us; speedup vs baseline: 8.2556x; 1.9669x over previous
//
#include <hip/hip_runtime.h>

#define N_NODES 100000
#define N_EDGES 1600000
#define IN_F 256
#define OUT_F 128

#define NB 512               // buckets (bucket = row / RPB); bucket 511 empty
#define RPB 196              // rows per bucket
#define NBUSED ((N_NODES + RPB - 1) / RPB)        // 511
#define TILE 8192
#define NTILES ((N_EDGES + TILE - 1) / TILE)      // 196

typedef unsigned long long ull;
typedef __attribute__((ext_vector_type(4))) float f32x4;
typedef __attribute__((ext_vector_type(8))) short bf16x8;

__device__ __forceinline__ unsigned short f2bf(float f) {
    unsigned u = __float_as_uint(f);
    unsigned r = u + 0x7FFF + ((u >> 16) & 1);    // round-to-nearest-even
    return (unsigned short)(r >> 16);
}

// ---------------------------------------------------------------------------
// W convert: Wt[n][k] = bf16(W[k][n])
// ---------------------------------------------------------------------------
__global__ __launch_bounds__(256) void wconv_kernel(const float* __restrict__ W,
                                                    unsigned short* __restrict__ Wt) {
    int idx = blockIdx.x * 256 + threadIdx.x;      // 32768 total
    int n = idx >> 8;
    int k = idx & 255;
    Wt[n * IN_F + k] = f2bf(W[k * OUT_F + n]);
}

// ---------------------------------------------------------------------------
// MFMA GEMM: support_bf[100000,128](bf16) = X[100000,256] @ W
// 128x128 tile, BK=32, 4 waves (2x2), 64x64 per wave.
// ---------------------------------------------------------------------------
__global__ __launch_bounds__(256) void gemm_mfma_kernel(const float* __restrict__ X,
                                                        const unsigned short* __restrict__ Wt,
                                                        unsigned short* __restrict__ support_bf) {
    __shared__ __align__(16) unsigned short Albs[4][128][8];   // 8 KB
    __shared__ __align__(16) unsigned short Blbs[4][128][8];   // 8 KB

    const int tid = threadIdx.x;
    const int block_row = blockIdx.x * 128;

    const int srow = tid >> 1;          // 0..127
    const int shalf = tid & 1;

    const int wid = tid >> 6;
    const int lane = tid & 63;
    const int wr = wid >> 1, wc = wid & 1;
    const int fr = lane & 15;
    const int kb = lane >> 4;

    const int agrow = block_row + srow;
    const float* xrow = X + (long)agrow * IN_F;
    const unsigned short* wrow = Wt + srow * IN_F;

    f32x4 acc[4][4];
#pragma unroll
    for (int m = 0; m < 4; ++m)
#pragma unroll
        for (int n = 0; n < 4; ++n) acc[m][n] = (f32x4)0.f;

    for (int k0 = 0; k0 < IN_F; k0 += 32) {
        float4 f0, f1, f2, f3;
        if (agrow < N_NODES) {
            f0 = *(const float4*)&xrow[k0 + shalf * 16 + 0];
            f1 = *(const float4*)&xrow[k0 + shalf * 16 + 4];
            f2 = *(const float4*)&xrow[k0 + shalf * 16 + 8];
            f3 = *(const float4*)&xrow[k0 + shalf * 16 + 12];
        } else {
            f0 = f1 = f2 = f3 = make_float4(0.f, 0.f, 0.f, 0.f);
        }
        {
            bf16x8 p0, p1;
            p0[0] = (short)f2bf(f0.x); p0[1] = (short)f2bf(f0.y);
            p0[2] = (short)f2bf(f0.z); p0[3] = (short)f2bf(f0.w);
            p0[4] = (short)f2bf(f1.x); p0[5] = (short)f2bf(f1.y);
            p0[6] = (short)f2bf(f1.z); p0[7] = (short)f2bf(f1.w);
            p1[0] = (short)f2bf(f2.x); p1[1] = (short)f2bf(f2.y);
            p1[2] = (short)f2bf(f2.z); p1[3] = (short)f2bf(f2.w);
            p1[4] = (short)f2bf(f3.x); p1[5] = (short)f2bf(f3.y);
            p1[6] = (short)f2bf(f3.z); p1[7] = (short)f2bf(f3.w);
            *(bf16x8*)&Albs[shalf * 2][srow][0]     = p0;
            *(bf16x8*)&Albs[shalf * 2 + 1][srow][0] = p1;
        }
        {
            bf16x8 b0 = *(const bf16x8*)&wrow[k0 + shalf * 16];
            bf16x8 b1 = *(const bf16x8*)&wrow[k0 + shalf * 16 + 8];
            *(bf16x8*)&Blbs[shalf * 2][srow][0]     = b0;
            *(bf16x8*)&Blbs[shalf * 2 + 1][srow][0] = b1;
        }
        __syncthreads();

        bf16x8 af[4], bfr[4];
#pragma unroll
        for (int m = 0; m < 4; ++m)
            af[m] = *(const bf16x8*)&Albs[kb][wr * 64 + m * 16 + fr][0];
#pragma unroll
        for (int n = 0; n < 4; ++n)
            bfr[n] = *(const bf16x8*)&Blbs[kb][wc * 64 + n * 16 + fr][0];
#pragma unroll
        for (int m = 0; m < 4; ++m)
#pragma unroll
            for (int n = 0; n < 4; ++n)
                acc[m][n] = __builtin_amdgcn_mfma_f32_16x16x32_bf16(af[m], bfr[n],
                                                                    acc[m][n], 0, 0, 0);
        __syncthreads();
    }

    // epilogue: C/D layout col=lane&15, row=(lane>>4)*4+reg ; write bf16
    const int crow0 = (lane >> 4) * 4;
    const int ccol = lane & 15;
#pragma unroll
    for (int m = 0; m < 4; ++m) {
#pragma unroll
        for (int reg = 0; reg < 4; ++reg) {
            int grow = block_row + wr * 64 + m * 16 + crow0 + reg;
            if (grow < N_NODES) {
#pragma unroll
                for (int n = 0; n < 4; ++n) {
                    int gcol = wc * 64 + n * 16 + ccol;
                    support_bf[(long)grow * OUT_F + gcol] = f2bf(acc[m][n][reg]);
                }
            }
        }
    }
}

// ---------------------------------------------------------------------------
// Bucket histogram (LDS-aggregated)
// ---------------------------------------------------------------------------
__global__ __launch_bounds__(1024) void bhist_kernel(const int* __restrict__ erow,
                                                     int* __restrict__ bucket_hist) {
    __shared__ int lh[NB];
    for (int i = threadIdx.x; i < NB; i += 1024) lh[i] = 0;
    __syncthreads();
    int e0 = blockIdx.x * TILE;
    int e1 = min(e0 + TILE, N_EDGES);
    for (int e = e0 + threadIdx.x; e < e1; e += 1024)
        atomicAdd(&lh[erow[e] / RPB], 1);
    __syncthreads();
    for (int i = threadIdx.x; i < NB; i += 1024)
        if (lh[i]) atomicAdd(&bucket_hist[i], lh[i]);
}

// ---------------------------------------------------------------------------
// Bucket scan (single block of 512)
// ---------------------------------------------------------------------------
__global__ __launch_bounds__(512) void bscan_kernel(const int* __restrict__ bucket_hist,
                                                    int* __restrict__ bucket_base,
                                                    int* __restrict__ bucket_cursor,
                                                    int* __restrict__ offsets) {
    __shared__ int p[512];
    const int tid = threadIdx.x;
    int v = bucket_hist[tid];
    p[tid] = v;
    __syncthreads();
#pragma unroll
    for (int off = 1; off < 512; off <<= 1) {
        int t = (tid >= off) ? p[tid - off] : 0;
        __syncthreads();
        p[tid] += t;
        __syncthreads();
    }
    bucket_base[tid] = p[tid] - v;
    bucket_cursor[tid] = p[tid] - v;
    if (tid == 511) bucket_base[512] = p[511];
    if (tid == 0) offsets[N_NODES] = N_EDGES;
}

// ---------------------------------------------------------------------------
// Pass 1: shuffle edges into bucket segments (coalesced-ish writes)
// record = [val:f32 (63:32) | localrow:8 (31:24) | col:24 (23:0)]
// ---------------------------------------------------------------------------
__global__ __launch_bounds__(1024) void shuffle_kernel(const int* __restrict__ erow,
                                                       const int* __restrict__ ecol,
                                                       const float* __restrict__ eval,
                                                       int* __restrict__ bucket_cursor,
                                                       ull* __restrict__ bucketed) {
    __shared__ int lhist[NB];
    __shared__ int lbase[NB];
    const int e0 = blockIdx.x * TILE;
    const int e1 = min(e0 + TILE, N_EDGES);

    for (int i = threadIdx.x; i < NB; i += 1024) lhist[i] = 0;
    __syncthreads();
    for (int e = e0 + threadIdx.x; e < e1; e += 1024)
        atomicAdd(&lhist[erow[e] / RPB], 1);
    __syncthreads();
    for (int i = threadIdx.x; i < NB; i += 1024) {
        int c = lhist[i];
        lbase[i] = c ? atomicAdd(&bucket_cursor[i], c) : 0;
        lhist[i] = 0;                      // reuse as local cursor
    }
    __syncthreads();
    for (int e = e0 + threadIdx.x; e < e1; e += 1024) {
        int row = erow[e];                 // L2-hot re-read
        int b = row / RPB;
        int lr = row - b * RPB;
        int pos = lbase[b] + atomicAdd(&lhist[b], 1);
        ull rec = ((ull)__float_as_uint(eval[e]) << 32) |
                  ((unsigned)lr << 24) | (unsigned)ecol[e];
        bucketed[pos] = rec;
    }
}

// ---------------------------------------------------------------------------
// Pass 2: per-bucket counting sort by local row; emits offsets + sorted recs.
// Bucket region is contiguous (~25 KB) -> single-XCD L2-local writes.
// ---------------------------------------------------------------------------
__global__ __launch_bounds__(256) void bsort_kernel(const int* __restrict__ bucket_base,
                                                    const ull* __restrict__ bucketed,
                                                    ull* __restrict__ sorted,
                                                    int* __restrict__ offsets) {
    const int b = blockIdx.x;
    const int r0 = b * RPB;
    if (r0 >= N_NODES) return;
    const int nrows = min(RPB, N_NODES - r0);
    const int start = bucket_base[b];
    const int cnt = bucket_base[b + 1] - start;

    __shared__ int lhist[RPB];
    __shared__ int lcur[RPB];
    __shared__ int lscan[256];
    const int tid = threadIdx.x;

    if (tid < RPB) lhist[tid] = 0;
    __syncthreads();
    for (int i = start + tid; i < start + cnt; i += 256) {
        int lr = (int)((bucketed[i] >> 24) & 0xFF);
        atomicAdd(&lhist[lr], 1);
    }
    __syncthreads();
    int v = (tid < RPB) ? lhist[tid] : 0;
    lscan[tid] = v;
    __syncthreads();
#pragma unroll
    for (int off = 1; off < 256; off <<= 1) {
        int t = (tid >= off) ? lscan[tid - off] : 0;
        __syncthreads();
        lscan[tid] += t;
        __syncthreads();
    }
    int excl = lscan[tid] - v;
    if (tid < nrows) {
        offsets[r0 + tid] = start + excl;
        lcur[tid] = excl;
    }
    __syncthreads();
    for (int i = start + tid; i < start + cnt; i += 256) {
        ull rec = bucketed[i];             // L2-hot second read
        int lr = (int)((rec >> 24) & 0xFF);
        int p = atomicAdd(&lcur[lr], 1);
        sorted[start + p] = rec;
    }
}

// ---------------------------------------------------------------------------
// SpMM: one wave per row; bf16 support gather; bias folded in.
// ---------------------------------------------------------------------------
__global__ __launch_bounds__(256) void spmm_kernel(const int* __restrict__ offsets,
                                                   const ull* __restrict__ sorted,
                                                   const unsigned short* __restrict__ sbf,
                                                   const float* __restrict__ b,
                                                   float* __restrict__ out) {
    const int wave = blockIdx.x * 4 + (threadIdx.x >> 6);
    const int lane = threadIdx.x & 63;
    if (wave >= N_NODES) return;

    const int row = wave;
    const int start = offsets[row];
    const int end = offsets[row + 1];

    float2 acc = *(const float2*)&b[lane * 2];

    int e = start;
    for (; e + 1 < end; e += 2) {
        ull r0 = sorted[e];
        ull r1 = sorted[e + 1];
        int c0 = (int)(r0 & 0xFFFFFF);
        int c1 = (int)(r1 & 0xFFFFFF);
        float v0 = __uint_as_float((unsigned)(r0 >> 32));
        float v1 = __uint_as_float((unsigned)(r1 >> 32));
        unsigned u0 = *(const unsigned*)&sbf[(long)c0 * OUT_F + lane * 2];
        unsigned u1 = *(const unsigned*)&sbf[(long)c1 * OUT_F + lane * 2];
        acc.x += v0 * __uint_as_float(u0 << 16) + v1 * __uint_as_float(u1 << 16);
        acc.y += v0 * __uint_as_float(u0 & 0xFFFF0000u) + v1 * __uint_as_float(u1 & 0xFFFF0000u);
    }
    if (e < end) {
        ull r0 = sorted[e];
        int c0 = (int)(r0 & 0xFFFFFF);
        float v0 = __uint_as_float((unsigned)(r0 >> 32));
        unsigned u0 = *(const unsigned*)&sbf[(long)c0 * OUT_F + lane * 2];
        acc.x += v0 * __uint_as_float(u0 << 16);
        acc.y += v0 * __uint_as_float(u0 & 0xFFFF0000u);
    }

    *(float2*)&out[row * OUT_F + lane * 2] = acc;
}

extern "C" void kernel_launch(void* const* d_in, const int* in_sizes, int n_in,
                              void* d_out, int out_size, void* d_ws, size_t ws_size,
                              hipStream_t stream) {
    const float* x        = (const float*)d_in[0];
    const int*   edge_row = (const int*)d_in[1];
    const int*   edge_col = (const int*)d_in[2];
    const float* edge_val = (const float*)d_in[3];
    const float* weight   = (const float*)d_in[4];
    const float* bias     = (const float*)d_in[5];
    float* out = (float*)d_out;

    // workspace layout
    unsigned short* support_bf = (unsigned short*)d_ws;        // 12,800,000 u16 = 25.6 MB
    int* base_i        = (int*)d_ws + 6400000;                 // after support
    int* bucket_hist   = base_i;                               // 512
    int* bucket_base   = base_i + 512;                         // 513
    int* bucket_cursor = base_i + 1032;                        // 512 (pad 513->520)
    int* offsets       = base_i + 1544;                        // 100,001 (pad->100002)
    ull* bucketed = (ull*)(base_i + 101546);                   // 1,600,000 u64 (8B aligned)
    ull* sorted   = bucketed + N_EDGES;                        // 1,600,000 u64
    unsigned short* wt = (unsigned short*)(sorted + N_EDGES);  // 32,768 u16
    // total ≈ 52 MB

    // 0) W -> transposed bf16
    wconv_kernel<<<dim3(128), 256, 0, stream>>>(weight, wt);

    // 1) support_bf = bf16(X @ W)
    gemm_mfma_kernel<<<dim3((N_NODES + 127) / 128), 256, 0, stream>>>(x, wt, support_bf);

    // 2) bucket histogram
    hipMemsetAsync(bucket_hist, 0, NB * sizeof(int), stream);
    bhist_kernel<<<dim3(NTILES), 1024, 0, stream>>>(edge_row, bucket_hist);

    // 3) bucket scan -> base/cursor; also offsets[N] = E
    bscan_kernel<<<dim3(1), 512, 0, stream>>>(bucket_hist, bucket_base, bucket_cursor, offsets);

    // 4) pass 1: shuffle into bucket segments
    shuffle_kernel<<<dim3(NTILES), 1024, 0, stream>>>(edge_row, edge_col, edge_val,
                                                      bucket_cursor, bucketed);

    // 5) pass 2: per-bucket counting sort -> sorted + offsets
    bsort_kernel<<<dim3(NBUSED), 256, 0, stream>>>(bucket_base, bucketed, sorted, offsets);

    // 6) SpMM
    spmm_kernel<<<dim3((N_NODES + 3) / 4), 256, 0, stream>>>(offsets, sorted, support_bf,
                                                             bias, out);
}